// Round 8
// baseline (852.993 us; speedup 1.0000x reference)
//
#include <hip/hip_runtime.h>

#define N_NODES 100000
#define N_EDGES 6400000
#define IN_CH 14
#define HID 16
#define OUT_CH 8

#define NBINS 1024
#define BINW 98             // 1024*98 = 100352 >= 100000
#define NCLS 8              // XCD classes (blockIdx & 7)
#define SLABC 1152          // words per (bin,class); mean 781, sigma ~28 (13-sigma cap)
#define BINREG (NCLS * SLABC)                  // 9216 words per bin region
#define BINBUF_WORDS (NBINS * BINREG)          // 9,437,184
#define SORT_CAP 7168       // LDS staging cap per bin; mean 6250, sigma ~79
#define BF_THREADS 1024
#define BF_TILE 8192
#define BF_EPT (BF_TILE / BF_THREADS)          // 8 edges/thread
#define N_TILES ((N_EDGES + BF_TILE - 1) / BF_TILE)   // 782
#define LHN 128             // pow2 >= BINW for the per-bin scan

// Lessons ledger:
//  r1: per-edge device-scope atomics = ~32B HBM RMW each. Never.
//  r2: gather lane-width (4B vs 8B) is not the limiter. Null.
//  r3: register staging / SW pipelining of gathers. Null.
//  r4: LDS float atomics serialize per active lane -> 100M of them = 500+us. Never.
//  r5: non-temporal loads on csr killed cross-group L2 line reuse. NT only for
//      truly single-touch streams.
//  r6: WIN (-8us): stage contiguous index runs in LDS; only irreducible row
//      gathers touch global.
//  r7: FAILED: hipLaunchCooperativeKernel rejected/misbehaved (out never
//      written; absmax == max|ref|). Unchecked cooperative launches are a trap.
//  r8: same fusion, MANUAL grid barrier + normal launch. Residency is
//      arithmetic: LDS 36.5KB*4=146KB<=160KB, launch_bounds(512,8) pins
//      VGPR<=64 -> 32 waves/CU -> 1024 blocks all resident. Release/acquire
//      fences (agent scope) handle the non-coherent per-XCD L2s.

// round-to-nearest-even fp32 -> bf16 (as ushort)
__device__ __forceinline__ unsigned short f2bf(float f) {
    unsigned u = __float_as_uint(f);
    u += 0x7fffu + ((u >> 16) & 1u);
    return (unsigned short)(u >> 16);
}

// ---------------------------------------------------------------------------
// prep: cast x to padded bf16 rows (16 ushorts, pad=0), zero the 8x1024 tail
// counters AND the grid-barrier word (workspace is 0xAA-poisoned per launch).
// ---------------------------------------------------------------------------
__global__ void prep_kernel(const float* __restrict__ x, unsigned short* __restrict__ xb,
                            int* __restrict__ tail, int* __restrict__ bar) {
    int i = blockIdx.x * blockDim.x + threadIdx.x;
    if (i == 0) *bar = 0;
    if (i < NCLS * NBINS) tail[i] = 0;
    if (i >= (NBINS * BINW) * 16) return;
    int n = i >> 4, c = i & 15;
    float v = (n < N_NODES && c < IN_CH) ? x[n * IN_CH + c] : 0.0f;
    xb[i] = f2bf(v);
}

// ---------------------------------------------------------------------------
// binfill: per 8192-edge tile, LDS counting-sort by bin, reserve a dense
// chunk in the bin's CLASS sub-slab (class = blockIdx&7 ~ XCD) via one tail
// atomic, then LINEAR write-out. Packed word: src [0,17) | local dst [17,24).
// (r0-exact, proven)
// ---------------------------------------------------------------------------
__global__ __launch_bounds__(BF_THREADS)
void binfill_kernel(const uint4* __restrict__ src4, const uint4* __restrict__ dst4,
                    int* __restrict__ tail, unsigned* __restrict__ binbuf) {
    __shared__ unsigned stile[BF_TILE];        // 32 KB sorted packed words
    __shared__ unsigned short stbin[BF_TILE];  // 16 KB bin id per sorted slot
    __shared__ int lh[NBINS];                  // 4 KB tile histogram
    __shared__ int lx[NBINS];                  // 4 KB exclusive offsets
    __shared__ int lofs[NBINS];                // 4 KB reserved sub-slab offsets
    __shared__ int wsum[16];

    const int t = threadIdx.x;
    const int lane = t & 63;
    const int wv = t >> 6;                     // 16 waves
    const int cls = blockIdx.x & (NCLS - 1);
    const long long tb = (long long)blockIdx.x * BF_TILE;

    lh[t] = 0;                                 // BF_THREADS == NBINS
    __syncthreads();

    unsigned epack[BF_EPT];
    int      ebin[BF_EPT];
    int      erank[BF_EPT];

#pragma unroll
    for (int sw = 0; sw < BF_EPT / 4; ++sw) {
        long long u = tb / 4 + (long long)sw * BF_THREADS + t;
        int k = sw * 4;
        if (u * 4 < N_EDGES) {
            uint4 s = src4[u];
            uint4 d = dst4[u];
            unsigned b;
            b = d.x / BINW; epack[k+0] = s.x | ((d.x - b*BINW) << 17); ebin[k+0] = (int)b; erank[k+0] = atomicAdd(&lh[b], 1);
            b = d.y / BINW; epack[k+1] = s.y | ((d.y - b*BINW) << 17); ebin[k+1] = (int)b; erank[k+1] = atomicAdd(&lh[b], 1);
            b = d.z / BINW; epack[k+2] = s.z | ((d.z - b*BINW) << 17); ebin[k+2] = (int)b; erank[k+2] = atomicAdd(&lh[b], 1);
            b = d.w / BINW; epack[k+3] = s.w | ((d.w - b*BINW) << 17); ebin[k+3] = (int)b; erank[k+3] = atomicAdd(&lh[b], 1);
        } else {
            ebin[k+0] = ebin[k+1] = ebin[k+2] = ebin[k+3] = -1;
        }
    }
    __syncthreads();

    // wave-level exclusive scan of lh (1024 entries, 16 waves)
    int v = lh[t];
    int incl = v;
#pragma unroll
    for (int d = 1; d < 64; d <<= 1) {
        int o = __shfl_up(incl, d, 64);
        if (lane >= d) incl += o;
    }
    if (lane == 63) wsum[wv] = incl;
    __syncthreads();
    if (t < 16) {
        int s = wsum[t];
        int si = s;
#pragma unroll
        for (int d = 1; d < 16; d <<= 1) {
            int o = __shfl_up(si, d, 16);
            if (t >= d) si += o;
        }
        wsum[t] = si - s;                      // exclusive wave offset
    }
    __syncthreads();
    lx[t] = incl - v + wsum[wv];               // exclusive within tile
    lofs[t] = atomicAdd(&tail[cls * NBINS + t], v);   // offset within sub-slab
    __syncthreads();

    // place into LDS sorted-by-bin order
#pragma unroll
    for (int k = 0; k < BF_EPT; ++k) {
        if (ebin[k] >= 0) {
            int pos = lx[ebin[k]] + erank[k];
            stile[pos] = epack[k];
            stbin[pos] = (unsigned short)ebin[k];
        }
    }
    __syncthreads();

    // linear coalesced write-out into per-(bin,class) sub-slabs
    int cnt = (int)((N_EDGES - tb < BF_TILE) ? (N_EDGES - tb) : BF_TILE);
    for (int i = t; i < cnt; i += BF_THREADS) {
        int b = stbin[i];
        int slot = lofs[b] + (i - lx[b]);
        if ((unsigned)slot < (unsigned)SLABC)  // deterministic: never overflows
            binbuf[b * BINREG + cls * SLABC + slot] = stile[i];
    }
}

// ---------------------------------------------------------------------------
// FUSED two-layer aggregation with MANUAL grid barrier. One block per bin,
// exactly 4 blocks/CU co-resident by construction (36.5KB LDS, VGPR<=64 via
// launch_bounds(512,8)). L1: sort bin edges into sbuf (persists), gather xb,
// MLP -> h. Barrier: release fence + device atomic arrive + acquire spin.
// L2: gather hb with the SAME in-LDS sorted index list, output MLP.
// ---------------------------------------------------------------------------
__global__ __launch_bounds__(512, 8)
void fusedagg_kernel(const unsigned* __restrict__ xb, const float* __restrict__ x,
                     const unsigned* __restrict__ binbuf, const int* __restrict__ tail,
                     const float* __restrict__ W1_l, const float* __restrict__ b1,
                     const float* __restrict__ W1_r,
                     float* __restrict__ h_f32, unsigned short* __restrict__ h_bf16,
                     const float* __restrict__ W2_l, const float* __restrict__ b2,
                     const float* __restrict__ W2_r, float* __restrict__ out,
                     int* __restrict__ bar) {
    __shared__ unsigned sbuf[SORT_CAP];        // 28,672 B — PERSISTS across layers
    __shared__ float smean[BINW * 16];         // 6,272 B — per-layer means
    __shared__ int lhist[LHN];
    __shared__ int loff[LHN];
    __shared__ int lcur[LHN];
    __shared__ int wtot[2];
    __shared__ int segcnt[NCLS];
    __shared__ int totc[1];

    const int b = blockIdx.x;
    const int t = threadIdx.x;
    const int regbase = b * BINREG;
    const int g = t >> 3;                      // 64 groups of 8 lanes
    const int l = t & 7;                       // lane l -> channels 2l, 2l+1

    // P0: per-class segment counts (8 parallel lane loads; t0 LDS-only scan —
    // same wave, program order; pattern proven in r3/r4 passing kernels)
    if (t < NCLS) {
        int c = tail[t * NBINS + b];
        if (c < 0) c = 0;
        if (c > SLABC) c = SLABC;
        segcnt[t] = c;
    }
    if (t < LHN) lhist[t] = 0;
    if (t == 0) {
        int s = 0;
        for (int k = 0; k < NCLS; ++k) {
            int c = segcnt[k];
            if (s + c > SORT_CAP) { c = SORT_CAP - s; segcnt[k] = c; }  // insurance
            s += c;
        }
        totc[0] = s;
    }
    __syncthreads();
    const int cnt = totc[0];

    // P1: local-node histogram over the 8 class segments
    for (int k = 0; k < NCLS; ++k) {
        const int base = regbase + k * SLABC;
        const int c = segcnt[k];
        for (int i = t; i < c; i += 512)
            atomicAdd(&lhist[binbuf[base + i] >> 17], 1);
    }
    __syncthreads();

    // P2: wave-level exclusive scan of 128 entries (LDS only)
    int v = (t < LHN) ? lhist[t] : 0;
    int incl = v;
#pragma unroll
    for (int d = 1; d < 64; d <<= 1) {
        int o = __shfl_up(incl, d, 64);
        if ((t & 63) >= d) incl += o;
    }
    if (t < LHN && (t & 63) == 63) wtot[t >> 6] = incl;
    __syncthreads();
    if (t < LHN) {
        int excl = incl - v + ((t >= 64) ? wtot[0] : 0);
        loff[t] = excl;
        lcur[t] = excl;
    }
    __syncthreads();

    // P3: rank & place sorted src indices into sbuf (masked, stays resident)
    for (int k = 0; k < NCLS; ++k) {
        const int base = regbase + k * SLABC;
        const int c = segcnt[k];
        for (int i = t; i < c; i += 512) {
            unsigned w = binbuf[base + i];
            unsigned ld = w >> 17;
            int pos = atomicAdd(&lcur[ld], 1);
            if (pos < cnt) sbuf[pos] = w & 0x1FFFFu;
        }
    }
    __syncthreads();

    // P5: layer-1 gather (xb rows, L2-resident) -> means
    float m0[2], m1[2];
#pragma unroll
    for (int p = 0; p < 2; ++p) {
        m0[p] = 0.0f; m1[p] = 0.0f;
        int n = g + 64 * p;
        if (n < BINW) {
            int dg = lhist[n];
            int off = loff[n];
            float a0 = 0.0f, a1 = 0.0f;
            int i = 0;
            for (; i + 4 <= dg; i += 4) {
                unsigned s0 = sbuf[off + i], s1 = sbuf[off + i + 1];
                unsigned s2 = sbuf[off + i + 2], s3 = sbuf[off + i + 3];
                unsigned u0 = xb[s0 * 8 + l];
                unsigned u1 = xb[s1 * 8 + l];
                unsigned u2 = xb[s2 * 8 + l];
                unsigned u3 = xb[s3 * 8 + l];
                a0 += __uint_as_float(u0 << 16);  a1 += __uint_as_float(u0 & 0xffff0000u);
                a0 += __uint_as_float(u1 << 16);  a1 += __uint_as_float(u1 & 0xffff0000u);
                a0 += __uint_as_float(u2 << 16);  a1 += __uint_as_float(u2 & 0xffff0000u);
                a0 += __uint_as_float(u3 << 16);  a1 += __uint_as_float(u3 & 0xffff0000u);
            }
            for (; i < dg; ++i) {
                unsigned u0 = xb[sbuf[off + i] * 8 + l];
                a0 += __uint_as_float(u0 << 16);  a1 += __uint_as_float(u0 & 0xffff0000u);
            }
            float inv = 1.0f / fmaxf((float)dg, 1.0f);
            m0[p] = a0 * inv; m1[p] = a1 * inv;
        }
    }
#pragma unroll
    for (int p = 0; p < 2; ++p) {
        int n = g + 64 * p;
        if (n < BINW) {
            smean[n * 16 + 2 * l]     = m0[p];
            smean[n * 16 + 2 * l + 1] = m1[p];
        }
    }
    __syncthreads();

    // P6: layer-1 MLP epilogue -> h_f32 + h_bf16 (global)
    const int nodeBase = b * BINW;
    for (int i = t; i < BINW * HID; i += 512) {
        int n = i >> 4, oc = i & 15;
        int gn = nodeBase + n;
        if (gn >= N_NODES) break;
        float a = b1[oc];
#pragma unroll
        for (int k = 0; k < IN_CH; ++k)
            a = fmaf(smean[n * 16 + k], W1_l[oc * IN_CH + k],
                     fmaf(x[gn * IN_CH + k], W1_r[oc * IN_CH + k], a));
        float vv = fmaxf(a, 0.0f);
        h_f32[gn * HID + oc] = vv;
        h_bf16[gn * HID + oc] = f2bf(vv);
    }

    // ---- manual grid barrier (single-use; bar zeroed by prep) ----
    __syncthreads();                 // all block threads' h stores issued
    __threadfence();                 // agent-scope release: L2 writeback
    if (t == 0) {
        __hip_atomic_fetch_add(bar, 1, __ATOMIC_ACQ_REL, __HIP_MEMORY_SCOPE_AGENT);
        while (__hip_atomic_load(bar, __ATOMIC_ACQUIRE, __HIP_MEMORY_SCOPE_AGENT) < NBINS)
            __builtin_amdgcn_s_sleep(8);
    }
    __syncthreads();                 // block waits for t0
    __threadfence();                 // agent-scope acquire: invalidate caches

    // P7: layer-2 gather (hb rows) using the SAME resident sbuf indices
    const unsigned* hb = (const unsigned*)h_bf16;
#pragma unroll
    for (int p = 0; p < 2; ++p) {
        m0[p] = 0.0f; m1[p] = 0.0f;
        int n = g + 64 * p;
        if (n < BINW) {
            int dg = lhist[n];
            int off = loff[n];
            float a0 = 0.0f, a1 = 0.0f;
            int i = 0;
            for (; i + 4 <= dg; i += 4) {
                unsigned s0 = sbuf[off + i], s1 = sbuf[off + i + 1];
                unsigned s2 = sbuf[off + i + 2], s3 = sbuf[off + i + 3];
                unsigned u0 = hb[s0 * 8 + l];
                unsigned u1 = hb[s1 * 8 + l];
                unsigned u2 = hb[s2 * 8 + l];
                unsigned u3 = hb[s3 * 8 + l];
                a0 += __uint_as_float(u0 << 16);  a1 += __uint_as_float(u0 & 0xffff0000u);
                a0 += __uint_as_float(u1 << 16);  a1 += __uint_as_float(u1 & 0xffff0000u);
                a0 += __uint_as_float(u2 << 16);  a1 += __uint_as_float(u2 & 0xffff0000u);
                a0 += __uint_as_float(u3 << 16);  a1 += __uint_as_float(u3 & 0xffff0000u);
            }
            for (; i < dg; ++i) {
                unsigned u0 = hb[sbuf[off + i] * 8 + l];
                a0 += __uint_as_float(u0 << 16);  a1 += __uint_as_float(u0 & 0xffff0000u);
            }
            float inv = 1.0f / fmaxf((float)dg, 1.0f);
            m0[p] = a0 * inv; m1[p] = a1 * inv;
        }
    }
    __syncthreads();
#pragma unroll
    for (int p = 0; p < 2; ++p) {
        int n = g + 64 * p;
        if (n < BINW) {
            smean[n * 16 + 2 * l]     = m0[p];
            smean[n * 16 + 2 * l + 1] = m1[p];
        }
    }
    __syncthreads();

    // P8: output MLP (h_f32 rows were written by THIS block -> L2-warm)
    for (int i = t; i < BINW * OUT_CH; i += 512) {
        int n = i >> 3, oc = i & 7;
        int gn = nodeBase + n;
        if (gn >= N_NODES) break;
        float a = b2[oc];
#pragma unroll
        for (int k = 0; k < HID; ++k)
            a = fmaf(smean[n * 16 + k], W2_l[oc * HID + k],
                     fmaf(h_f32[gn * HID + k], W2_r[oc * HID + k], a));
        out[gn * OUT_CH + oc] = a;
    }
}

extern "C" void kernel_launch(void* const* d_in, const int* in_sizes, int n_in,
                              void* d_out, int out_size, void* d_ws, size_t ws_size,
                              hipStream_t stream) {
    const float* x    = (const float*)d_in[0];
    const int* eidx   = (const int*)d_in[1];
    const float* W1_l = (const float*)d_in[3];
    const float* b1   = (const float*)d_in[4];
    const float* W1_r = (const float*)d_in[5];
    const float* W2_l = (const float*)d_in[6];
    const float* b2   = (const float*)d_in[7];
    const float* W2_r = (const float*)d_in[8];
    float* out = (float*)d_out;

    const uint4* src4 = (const uint4*)eidx;
    const uint4* dst4 = (const uint4*)(eidx + N_EDGES);

    // Workspace layout (4-byte words):
    //   binbuf  @ 0           (9,437,184)  1024 bin regions of 8x1152 words
    //   tail    @ 9,437,184   (8,192)      zeroed by prep
    //   xb      @ 9,445,376   (802,816)    bf16 x rows (16 ush = 8 words/row)
    //   hb      @ 10,248,192  (800,000)    bf16 h rows
    //   h_f32   @ 11,048,192  (1,600,000)
    //   bar     @ 12,648,192  (1)          grid-barrier word, zeroed by prep
    int*            wsi      = (int*)d_ws;
    unsigned*       binbuf   = (unsigned*)wsi;
    int*            tail     = wsi + 9437184;
    unsigned short* x_bf16   = (unsigned short*)(wsi + 9445376);
    unsigned short* h_bf16   = (unsigned short*)(wsi + 10248192);
    float*          h_f32    = (float*)(wsi + 11048192);
    int*            bar      = wsi + 12648192;

    prep_kernel<<<(NBINS * BINW * 16 + 1023) / 1024, 1024, 0, stream>>>(x, x_bf16, tail, bar);
    binfill_kernel<<<N_TILES, BF_THREADS, 0, stream>>>(src4, dst4, tail, binbuf);
    fusedagg_kernel<<<NBINS, 512, 0, stream>>>((const unsigned*)x_bf16, x, binbuf, tail,
                                               W1_l, b1, W1_r, h_f32, h_bf16,
                                               W2_l, b2, W2_r, out, bar);
}

// Round 9
// 439.805 us; speedup vs baseline: 1.9395x; 1.9395x over previous
//
#include <hip/hip_runtime.h>

#define N_NODES 100000
#define N_EDGES 6400000
#define IN_CH 14
#define HID 16
#define OUT_CH 8

#define NBINS 1024
#define BINW 98             // 1024*98 = 100352 >= 100000
#define NCLS 8              // XCD classes (blockIdx & 7)
#define SLABC 1152          // words per (bin,class); mean 781, sigma ~28 (13-sigma cap)
#define BINREG (NCLS * SLABC)                  // 9216 words per bin region
#define BINBUF_WORDS (NBINS * BINREG)          // 9,437,184
#define SORT_CAP 7168       // LDS staging cap per bin; mean 6250, sigma ~79
#define BF_THREADS 1024
#define BF_TILE 8192
#define BF_EPT (BF_TILE / BF_THREADS)          // 8 edges/thread
#define N_TILES ((N_EDGES + BF_TILE - 1) / BF_TILE)   // 782
#define LHN 128             // pow2 >= BINW for the per-bin scan

// Lessons ledger:
//  r1: per-edge device-scope atomics = ~32B HBM RMW each. Never.
//  r2: gather lane-width (4B vs 8B) is not the limiter. Null.
//  r3: register staging / SW pipelining of gathers. Null.
//  r4: LDS float atomics serialize per active lane -> 100M = 500+us. Never.
//  r5: non-temporal loads on csr killed cross-group L2 line reuse. NT only for
//      truly single-touch streams.
//  r6: WIN (-8us): stage contiguous index runs in LDS; only irreducible row
//      gathers touch global.
//  r7: FAILED: unchecked hipLaunchCooperativeKernel (out never written).
//  r8: fusion CORRECT but 667us: ACQUIRE inside the spin loop = L2 invalidate
//      per poll x 128 blocks/XCD = L2 wiped every ~12cy during the whole
//      arrival window -> all work at HBM latency. NEVER acquire-in-loop.
//  r9: poll RELAXED (no cache maintenance), single release fence before
//      arrive + single acquire fence after exit. 2 fences/block total.

// round-to-nearest-even fp32 -> bf16 (as ushort)
__device__ __forceinline__ unsigned short f2bf(float f) {
    unsigned u = __float_as_uint(f);
    u += 0x7fffu + ((u >> 16) & 1u);
    return (unsigned short)(u >> 16);
}

// ---------------------------------------------------------------------------
// prep: cast x to padded bf16 rows (16 ushorts, pad=0), zero the 8x1024 tail
// counters AND the grid-barrier word (workspace is 0xAA-poisoned per launch).
// ---------------------------------------------------------------------------
__global__ void prep_kernel(const float* __restrict__ x, unsigned short* __restrict__ xb,
                            int* __restrict__ tail, int* __restrict__ bar) {
    int i = blockIdx.x * blockDim.x + threadIdx.x;
    if (i == 0) *bar = 0;
    if (i < NCLS * NBINS) tail[i] = 0;
    if (i >= (NBINS * BINW) * 16) return;
    int n = i >> 4, c = i & 15;
    float v = (n < N_NODES && c < IN_CH) ? x[n * IN_CH + c] : 0.0f;
    xb[i] = f2bf(v);
}

// ---------------------------------------------------------------------------
// binfill: per 8192-edge tile, LDS counting-sort by bin, reserve a dense
// chunk in the bin's CLASS sub-slab (class = blockIdx&7 ~ XCD) via one tail
// atomic, then LINEAR write-out. Packed word: src [0,17) | local dst [17,24).
// (r0-exact, proven)
// ---------------------------------------------------------------------------
__global__ __launch_bounds__(BF_THREADS)
void binfill_kernel(const uint4* __restrict__ src4, const uint4* __restrict__ dst4,
                    int* __restrict__ tail, unsigned* __restrict__ binbuf) {
    __shared__ unsigned stile[BF_TILE];        // 32 KB sorted packed words
    __shared__ unsigned short stbin[BF_TILE];  // 16 KB bin id per sorted slot
    __shared__ int lh[NBINS];                  // 4 KB tile histogram
    __shared__ int lx[NBINS];                  // 4 KB exclusive offsets
    __shared__ int lofs[NBINS];                // 4 KB reserved sub-slab offsets
    __shared__ int wsum[16];

    const int t = threadIdx.x;
    const int lane = t & 63;
    const int wv = t >> 6;                     // 16 waves
    const int cls = blockIdx.x & (NCLS - 1);
    const long long tb = (long long)blockIdx.x * BF_TILE;

    lh[t] = 0;                                 // BF_THREADS == NBINS
    __syncthreads();

    unsigned epack[BF_EPT];
    int      ebin[BF_EPT];
    int      erank[BF_EPT];

#pragma unroll
    for (int sw = 0; sw < BF_EPT / 4; ++sw) {
        long long u = tb / 4 + (long long)sw * BF_THREADS + t;
        int k = sw * 4;
        if (u * 4 < N_EDGES) {
            uint4 s = src4[u];
            uint4 d = dst4[u];
            unsigned b;
            b = d.x / BINW; epack[k+0] = s.x | ((d.x - b*BINW) << 17); ebin[k+0] = (int)b; erank[k+0] = atomicAdd(&lh[b], 1);
            b = d.y / BINW; epack[k+1] = s.y | ((d.y - b*BINW) << 17); ebin[k+1] = (int)b; erank[k+1] = atomicAdd(&lh[b], 1);
            b = d.z / BINW; epack[k+2] = s.z | ((d.z - b*BINW) << 17); ebin[k+2] = (int)b; erank[k+2] = atomicAdd(&lh[b], 1);
            b = d.w / BINW; epack[k+3] = s.w | ((d.w - b*BINW) << 17); ebin[k+3] = (int)b; erank[k+3] = atomicAdd(&lh[b], 1);
        } else {
            ebin[k+0] = ebin[k+1] = ebin[k+2] = ebin[k+3] = -1;
        }
    }
    __syncthreads();

    // wave-level exclusive scan of lh (1024 entries, 16 waves)
    int v = lh[t];
    int incl = v;
#pragma unroll
    for (int d = 1; d < 64; d <<= 1) {
        int o = __shfl_up(incl, d, 64);
        if (lane >= d) incl += o;
    }
    if (lane == 63) wsum[wv] = incl;
    __syncthreads();
    if (t < 16) {
        int s = wsum[t];
        int si = s;
#pragma unroll
        for (int d = 1; d < 16; d <<= 1) {
            int o = __shfl_up(si, d, 16);
            if (t >= d) si += o;
        }
        wsum[t] = si - s;                      // exclusive wave offset
    }
    __syncthreads();
    lx[t] = incl - v + wsum[wv];               // exclusive within tile
    lofs[t] = atomicAdd(&tail[cls * NBINS + t], v);   // offset within sub-slab
    __syncthreads();

    // place into LDS sorted-by-bin order
#pragma unroll
    for (int k = 0; k < BF_EPT; ++k) {
        if (ebin[k] >= 0) {
            int pos = lx[ebin[k]] + erank[k];
            stile[pos] = epack[k];
            stbin[pos] = (unsigned short)ebin[k];
        }
    }
    __syncthreads();

    // linear coalesced write-out into per-(bin,class) sub-slabs
    int cnt = (int)((N_EDGES - tb < BF_TILE) ? (N_EDGES - tb) : BF_TILE);
    for (int i = t; i < cnt; i += BF_THREADS) {
        int b = stbin[i];
        int slot = lofs[b] + (i - lx[b]);
        if ((unsigned)slot < (unsigned)SLABC)  // deterministic: never overflows
            binbuf[b * BINREG + cls * SLABC + slot] = stile[i];
    }
}

// ---------------------------------------------------------------------------
// FUSED two-layer aggregation with MANUAL grid barrier (r9: relaxed-poll).
// One block per bin, exactly 4 blocks/CU co-resident by construction
// (36.5KB LDS, VGPR<=64 via launch_bounds(512,8)).
// ---------------------------------------------------------------------------
__global__ __launch_bounds__(512, 8)
void fusedagg_kernel(const unsigned* __restrict__ xb, const float* __restrict__ x,
                     const unsigned* __restrict__ binbuf, const int* __restrict__ tail,
                     const float* __restrict__ W1_l, const float* __restrict__ b1,
                     const float* __restrict__ W1_r,
                     float* __restrict__ h_f32, unsigned short* __restrict__ h_bf16,
                     const float* __restrict__ W2_l, const float* __restrict__ b2,
                     const float* __restrict__ W2_r, float* __restrict__ out,
                     int* __restrict__ bar) {
    __shared__ unsigned sbuf[SORT_CAP];        // 28,672 B — PERSISTS across layers
    __shared__ float smean[BINW * 16];         // 6,272 B — per-layer means
    __shared__ int lhist[LHN];
    __shared__ int loff[LHN];
    __shared__ int lcur[LHN];
    __shared__ int wtot[2];
    __shared__ int segcnt[NCLS];
    __shared__ int totc[1];

    const int b = blockIdx.x;
    const int t = threadIdx.x;
    const int regbase = b * BINREG;
    const int g = t >> 3;                      // 64 groups of 8 lanes
    const int l = t & 7;                       // lane l -> channels 2l, 2l+1

    // P0: per-class segment counts (8 parallel lane loads; t0 LDS-only scan)
    if (t < NCLS) {
        int c = tail[t * NBINS + b];
        if (c < 0) c = 0;
        if (c > SLABC) c = SLABC;
        segcnt[t] = c;
    }
    if (t < LHN) lhist[t] = 0;
    if (t == 0) {
        int s = 0;
        for (int k = 0; k < NCLS; ++k) {
            int c = segcnt[k];
            if (s + c > SORT_CAP) { c = SORT_CAP - s; segcnt[k] = c; }  // insurance
            s += c;
        }
        totc[0] = s;
    }
    __syncthreads();
    const int cnt = totc[0];

    // P1: local-node histogram over the 8 class segments
    for (int k = 0; k < NCLS; ++k) {
        const int base = regbase + k * SLABC;
        const int c = segcnt[k];
        for (int i = t; i < c; i += 512)
            atomicAdd(&lhist[binbuf[base + i] >> 17], 1);
    }
    __syncthreads();

    // P2: wave-level exclusive scan of 128 entries (LDS only)
    int v = (t < LHN) ? lhist[t] : 0;
    int incl = v;
#pragma unroll
    for (int d = 1; d < 64; d <<= 1) {
        int o = __shfl_up(incl, d, 64);
        if ((t & 63) >= d) incl += o;
    }
    if (t < LHN && (t & 63) == 63) wtot[t >> 6] = incl;
    __syncthreads();
    if (t < LHN) {
        int excl = incl - v + ((t >= 64) ? wtot[0] : 0);
        loff[t] = excl;
        lcur[t] = excl;
    }
    __syncthreads();

    // P3: rank & place sorted src indices into sbuf (masked, stays resident)
    for (int k = 0; k < NCLS; ++k) {
        const int base = regbase + k * SLABC;
        const int c = segcnt[k];
        for (int i = t; i < c; i += 512) {
            unsigned w = binbuf[base + i];
            unsigned ld = w >> 17;
            int pos = atomicAdd(&lcur[ld], 1);
            if (pos < cnt) sbuf[pos] = w & 0x1FFFFu;
        }
    }
    __syncthreads();

    // P5: layer-1 gather (xb rows, L2-resident) -> means
    float m0[2], m1[2];
#pragma unroll
    for (int p = 0; p < 2; ++p) {
        m0[p] = 0.0f; m1[p] = 0.0f;
        int n = g + 64 * p;
        if (n < BINW) {
            int dg = lhist[n];
            int off = loff[n];
            float a0 = 0.0f, a1 = 0.0f;
            int i = 0;
            for (; i + 4 <= dg; i += 4) {
                unsigned s0 = sbuf[off + i], s1 = sbuf[off + i + 1];
                unsigned s2 = sbuf[off + i + 2], s3 = sbuf[off + i + 3];
                unsigned u0 = xb[s0 * 8 + l];
                unsigned u1 = xb[s1 * 8 + l];
                unsigned u2 = xb[s2 * 8 + l];
                unsigned u3 = xb[s3 * 8 + l];
                a0 += __uint_as_float(u0 << 16);  a1 += __uint_as_float(u0 & 0xffff0000u);
                a0 += __uint_as_float(u1 << 16);  a1 += __uint_as_float(u1 & 0xffff0000u);
                a0 += __uint_as_float(u2 << 16);  a1 += __uint_as_float(u2 & 0xffff0000u);
                a0 += __uint_as_float(u3 << 16);  a1 += __uint_as_float(u3 & 0xffff0000u);
            }
            for (; i < dg; ++i) {
                unsigned u0 = xb[sbuf[off + i] * 8 + l];
                a0 += __uint_as_float(u0 << 16);  a1 += __uint_as_float(u0 & 0xffff0000u);
            }
            float inv = 1.0f / fmaxf((float)dg, 1.0f);
            m0[p] = a0 * inv; m1[p] = a1 * inv;
        }
    }
#pragma unroll
    for (int p = 0; p < 2; ++p) {
        int n = g + 64 * p;
        if (n < BINW) {
            smean[n * 16 + 2 * l]     = m0[p];
            smean[n * 16 + 2 * l + 1] = m1[p];
        }
    }
    __syncthreads();

    // P6: layer-1 MLP epilogue -> h_f32 + h_bf16 (global)
    const int nodeBase = b * BINW;
    for (int i = t; i < BINW * HID; i += 512) {
        int n = i >> 4, oc = i & 15;
        int gn = nodeBase + n;
        if (gn >= N_NODES) break;
        float a = b1[oc];
#pragma unroll
        for (int k = 0; k < IN_CH; ++k)
            a = fmaf(smean[n * 16 + k], W1_l[oc * IN_CH + k],
                     fmaf(x[gn * IN_CH + k], W1_r[oc * IN_CH + k], a));
        float vv = fmaxf(a, 0.0f);
        h_f32[gn * HID + oc] = vv;
        h_bf16[gn * HID + oc] = f2bf(vv);
    }

    // ---- manual grid barrier, r9 protocol ----
    // syncthreads drains the block's stores (compiler emits vmcnt(0) before
    // s_barrier); t0 then: ONE release fence -> relaxed arrive -> RELAXED
    // poll (no cache maintenance per iteration!) -> ONE acquire fence.
    __syncthreads();
    if (t == 0) {
        __threadfence();             // release: writeback this XCD's L2 once
        __hip_atomic_fetch_add(bar, 1, __ATOMIC_RELAXED, __HIP_MEMORY_SCOPE_AGENT);
        while (__hip_atomic_load(bar, __ATOMIC_RELAXED, __HIP_MEMORY_SCOPE_AGENT) < NBINS)
            __builtin_amdgcn_s_sleep(32);
        __threadfence();             // acquire: invalidate L1/L2 once
    }
    __syncthreads();                 // releases the other 511 threads

    // P7: layer-2 gather (hb rows) using the SAME resident sbuf indices
    const unsigned* hb = (const unsigned*)h_bf16;
#pragma unroll
    for (int p = 0; p < 2; ++p) {
        m0[p] = 0.0f; m1[p] = 0.0f;
        int n = g + 64 * p;
        if (n < BINW) {
            int dg = lhist[n];
            int off = loff[n];
            float a0 = 0.0f, a1 = 0.0f;
            int i = 0;
            for (; i + 4 <= dg; i += 4) {
                unsigned s0 = sbuf[off + i], s1 = sbuf[off + i + 1];
                unsigned s2 = sbuf[off + i + 2], s3 = sbuf[off + i + 3];
                unsigned u0 = hb[s0 * 8 + l];
                unsigned u1 = hb[s1 * 8 + l];
                unsigned u2 = hb[s2 * 8 + l];
                unsigned u3 = hb[s3 * 8 + l];
                a0 += __uint_as_float(u0 << 16);  a1 += __uint_as_float(u0 & 0xffff0000u);
                a0 += __uint_as_float(u1 << 16);  a1 += __uint_as_float(u1 & 0xffff0000u);
                a0 += __uint_as_float(u2 << 16);  a1 += __uint_as_float(u2 & 0xffff0000u);
                a0 += __uint_as_float(u3 << 16);  a1 += __uint_as_float(u3 & 0xffff0000u);
            }
            for (; i < dg; ++i) {
                unsigned u0 = hb[sbuf[off + i] * 8 + l];
                a0 += __uint_as_float(u0 << 16);  a1 += __uint_as_float(u0 & 0xffff0000u);
            }
            float inv = 1.0f / fmaxf((float)dg, 1.0f);
            m0[p] = a0 * inv; m1[p] = a1 * inv;
        }
    }
    __syncthreads();
#pragma unroll
    for (int p = 0; p < 2; ++p) {
        int n = g + 64 * p;
        if (n < BINW) {
            smean[n * 16 + 2 * l]     = m0[p];
            smean[n * 16 + 2 * l + 1] = m1[p];
        }
    }
    __syncthreads();

    // P8: output MLP
    for (int i = t; i < BINW * OUT_CH; i += 512) {
        int n = i >> 3, oc = i & 7;
        int gn = nodeBase + n;
        if (gn >= N_NODES) break;
        float a = b2[oc];
#pragma unroll
        for (int k = 0; k < HID; ++k)
            a = fmaf(smean[n * 16 + k], W2_l[oc * HID + k],
                     fmaf(h_f32[gn * HID + k], W2_r[oc * HID + k], a));
        out[gn * OUT_CH + oc] = a;
    }
}

extern "C" void kernel_launch(void* const* d_in, const int* in_sizes, int n_in,
                              void* d_out, int out_size, void* d_ws, size_t ws_size,
                              hipStream_t stream) {
    const float* x    = (const float*)d_in[0];
    const int* eidx   = (const int*)d_in[1];
    const float* W1_l = (const float*)d_in[3];
    const float* b1   = (const float*)d_in[4];
    const float* W1_r = (const float*)d_in[5];
    const float* W2_l = (const float*)d_in[6];
    const float* b2   = (const float*)d_in[7];
    const float* W2_r = (const float*)d_in[8];
    float* out = (float*)d_out;

    const uint4* src4 = (const uint4*)eidx;
    const uint4* dst4 = (const uint4*)(eidx + N_EDGES);

    // Workspace layout (4-byte words):
    //   binbuf  @ 0           (9,437,184)  1024 bin regions of 8x1152 words
    //   tail    @ 9,437,184   (8,192)      zeroed by prep
    //   xb      @ 9,445,376   (802,816)    bf16 x rows (16 ush = 8 words/row)
    //   hb      @ 10,248,192  (800,000)    bf16 h rows
    //   h_f32   @ 11,048,192  (1,600,000)
    //   bar     @ 12,648,192  (1)          grid-barrier word, zeroed by prep
    int*            wsi      = (int*)d_ws;
    unsigned*       binbuf   = (unsigned*)wsi;
    int*            tail     = wsi + 9437184;
    unsigned short* x_bf16   = (unsigned short*)(wsi + 9445376);
    unsigned short* h_bf16   = (unsigned short*)(wsi + 10248192);
    float*          h_f32    = (float*)(wsi + 11048192);
    int*            bar      = wsi + 12648192;

    prep_kernel<<<(NBINS * BINW * 16 + 1023) / 1024, 1024, 0, stream>>>(x, x_bf16, tail, bar);
    binfill_kernel<<<N_TILES, BF_THREADS, 0, stream>>>(src4, dst4, tail, binbuf);
    fusedagg_kernel<<<NBINS, 512, 0, stream>>>((const unsigned*)x_bf16, x, binbuf, tail,
                                               W1_l, b1, W1_r, h_f32, h_bf16,
                                               W2_l, b2, W2_r, out, bar);
}